// Round 8
// baseline (139.701 us; speedup 1.0000x reference)
//
#include <hip/hip_runtime.h>
#include <hip/hip_bf16.h>
#include <cstdint>
#include <cstddef>

#define M_DIM 4096
#define N_DIM 4096
#define K_DIM 4096
#define NT    (K_DIM / 128)   // 32 K-tiles of BK=128

using i32x4  = __attribute__((ext_vector_type(4))) int;
using s8x16  = __attribute__((ext_vector_type(16))) char;
using float4v = __attribute__((ext_vector_type(4))) float;

__device__ __forceinline__ void gload_lds16(const void* g, void* l) {
    __builtin_amdgcn_global_load_lds(
        (const __attribute__((address_space(1))) uint32_t*)g,
        (__attribute__((address_space(3))) uint32_t*)l, 16, 0, 0);
}

__device__ __forceinline__ i32x4 mfma_i8(i32x4 a, i32x4 b, i32x4 c) {
    return __builtin_amdgcn_mfma_i32_16x16x64_i8(a, b, c, 0, 0, 0);
}

// ------------- pass 1a: x (f32) -> i8  q = clamp(rint(32x), ±127) -------------
__global__ __launch_bounds__(256) void cvt_x_kernel(const float* __restrict__ x,
                                                    char* __restrict__ xq,
                                                    int n16) {
    int idx = blockIdx.x * blockDim.x + threadIdx.x;
    int stride = gridDim.x * blockDim.x;
    for (int i = idx; i < n16; i += stride) {
        const float4v* p = (const float4v*)(x + (size_t)i * 16);
        s8x16 o;
#pragma unroll
        for (int v = 0; v < 4; ++v) {
            float4v f = p[v];
#pragma unroll
            for (int j = 0; j < 4; ++j) {
                float q = __builtin_rintf(f[j] * 32.0f);
                q = fminf(127.0f, fmaxf(-127.0f, q));
                o[v * 4 + j] = (char)(int)q;
            }
        }
        *(s8x16*)(xq + (size_t)i * 16) = o;
    }
}

// ------ pass 1b: W (K x N, f32) -> sign -> i8, TRANSPOSED to N x K ------
__global__ __launch_bounds__(256) void sign_wt_kernel(const float* __restrict__ W,
                                                      char* __restrict__ WqT) {
    __shared__ char tile[64][68];
    int j0 = blockIdx.x * 64;
    int k0 = blockIdx.y * 64;
    int tx = threadIdx.x;
    int ty = threadIdx.y;
#pragma unroll
    for (int i = 0; i < 16; ++i) {
        int kk = ty + i * 4;
        float w = W[(size_t)(k0 + kk) * N_DIM + (j0 + tx)];
        tile[kk][tx] = (char)((w > 0.f) - (w < 0.f));
    }
    __syncthreads();
#pragma unroll
    for (int i = 0; i < 16; ++i) {
        int jj = ty + i * 4;
        WqT[(size_t)(j0 + jj) * K_DIM + (k0 + tx)] = tile[tx][jj];
    }
}

// ---------------- pass 2: 256x256-tile i8 MFMA GEMM, BK=128 ----------------
// 4 waves (2x2), per-wave output 128x128 (acc 256 regs), 1 wave/SIMD.
// LDS traffic: 128 KB/tile reads (35% less than 8-wave 2x4) -> MFMA-bound.
// Overlap via within-wave ILP: interleaved ds_reads + independent MFMAs,
// compiler-counted lgkmcnt. 2-phase tile: stage(kt+1) early, compute,
// vmcnt(0)+barrier (loads have whole tile to land). No setprio (1 wave/SIMD).
//
// LDS granules (R5-verified c-major): granule(rb,kk) = 1024B = 16 rows x 64 k,
// slot l*16 <-> (row=l&15, k16=l>>4). A: 32 granules (rb 0..15, kk 0..1) at
// g*1024; B same at +65536. Fragment read = granule base + l*16 (conflict-free).
// Staging: wave wid, instr i: granule g = i*4+wid -> rb = i*2+(wid>>1),
// kk = wid&1. 8 A + 8 B gload16 per thread per tile.

#define SCHED0 __builtin_amdgcn_sched_barrier(0)

#define STAGE(p, kt) do {                                                        \
    _Pragma("unroll")                                                            \
    for (int i = 0; i < 8; ++i)                                                  \
        gload_lds16(AsrcW + (size_t)i * 32 * K_DIM + (size_t)(kt) * 128,         \
                    AdstW + (p) * 32768 + i * 4096);                             \
    _Pragma("unroll")                                                            \
    for (int i = 0; i < 8; ++i)                                                  \
        gload_lds16(BsrcW + (size_t)i * 32 * K_DIM + (size_t)(kt) * 128,         \
                    BdstW + (p) * 32768 + i * 4096);                             \
} while (0)

#define PHASE(p, kk) do {                                                        \
    _Pragma("unroll")                                                            \
    for (int m = 0; m < 8; ++m) {                                                \
        aF[m] = *(const i32x4*)(aRd + (p) * 32768 + m * 2048 + (kk) * 1024);     \
        bF[m] = *(const i32x4*)(bRd + (p) * 32768 + m * 2048 + (kk) * 1024);     \
    }                                                                            \
    _Pragma("unroll")                                                            \
    for (int mq = 0; mq < 8; ++mq)                                               \
        _Pragma("unroll")                                                        \
        for (int nq = 0; nq < 8; ++nq)                                           \
            acc[mq][nq] = mfma_i8(aF[mq], bF[nq], acc[mq][nq]);                  \
} while (0)

#define TILE(kt, p) do {                                                         \
    if ((kt) + 1 < NT) STAGE((p) ^ 1, (kt) + 1);                                 \
    SCHED0;                                                                      \
    PHASE(p, 0);                                                                 \
    PHASE(p, 1);                                                                 \
    asm volatile("s_waitcnt vmcnt(0)" ::: "memory");                             \
    __builtin_amdgcn_s_barrier();                                                \
    SCHED0;                                                                      \
} while (0)

__global__ __launch_bounds__(256, 1) void gemm_bin_kernel(const char* __restrict__ A,  // M x K i8
                                                          const char* __restrict__ B,  // N x K i8
                                                          const float* __restrict__ bias,
                                                          float* __restrict__ C) {
    // 128 KiB: A[2 buf][32 granules x 1024B], B same at +65536
    __shared__ __align__(16) unsigned char lds[131072];

    // T1: XCD-aware bijective swizzle (256 wgs, 256 % 8 == 0)
    int bid  = blockIdx.x;
    int swz  = (bid & 7) * 32 + (bid >> 3);
    int brow = (swz >> 4) << 8;
    int bcol = (swz & 15) << 8;

    int t    = threadIdx.x;
    int l    = t & 63;
    int wid  = t >> 6;     // 0..3
    int wr   = wid >> 1;   // 0..1  (M half: rows wr*128..+128)
    int wc   = wid & 1;    // 0..1  (N half: cols wc*128..+128)

    int lrow = l & 15;     // row within granule
    int klo  = l >> 4;     // 16B k-chunk within granule (0..3)

    // staging invariants: wave wid stages kk = wid&1, rb = (wid>>1) + 2i
    const char* AsrcW = A + (size_t)(brow + (wid >> 1) * 16 + lrow) * K_DIM
                          + (wid & 1) * 64 + klo * 16;
    const char* BsrcW = B + (size_t)(bcol + (wid >> 1) * 16 + lrow) * K_DIM
                          + (wid & 1) * 64 + klo * 16;
    unsigned char* AdstW = lds + wid * 1024 + l * 16;
    unsigned char* BdstW = lds + 65536 + wid * 1024 + l * 16;

    // fragment-read invariants
    const char* ldsc = (const char*)lds;
    const char* aRd = ldsc + wr * 16384 + l * 16;           // + p*32768 + mq*2048 + kk*1024
    const char* bRd = ldsc + 65536 + wc * 16384 + l * 16;   // + p*32768 + nq*2048 + kk*1024

    i32x4 acc[8][8];
#pragma unroll
    for (int i = 0; i < 8; ++i)
#pragma unroll
        for (int j = 0; j < 8; ++j)
            acc[i][j] = (i32x4){0, 0, 0, 0};

    i32x4 aF[8], bF[8];

    // prologue: stage tile 0 into buf 0; wait; barrier
    STAGE(0, 0);
    asm volatile("s_waitcnt vmcnt(0)" ::: "memory");
    __builtin_amdgcn_s_barrier();
    SCHED0;

    for (int kt2 = 0; kt2 < NT; kt2 += 2) {
        TILE(kt2, 0);
        TILE(kt2 + 1, 1);
    }

    // epilogue: C/D layout col=lane&15, row=(lane>>4)*4+reg; dequant 1/32
    float bv[8];
#pragma unroll
    for (int nq = 0; nq < 8; ++nq)
        bv[nq] = bias[bcol + wc * 128 + nq * 16 + lrow];
    int crow0 = brow + wr * 128 + klo * 4;
    int ccol0 = bcol + wc * 128 + lrow;
#pragma unroll
    for (int mq = 0; mq < 8; ++mq) {
#pragma unroll
        for (int nq = 0; nq < 8; ++nq) {
            int col = ccol0 + nq * 16;
#pragma unroll
            for (int r = 0; r < 4; ++r) {
                int row = crow0 + mq * 16 + r;
                C[(size_t)row * N_DIM + col] =
                    (float)acc[mq][nq][r] * 0.03125f + bv[nq];
            }
        }
    }
}

extern "C" void kernel_launch(void* const* d_in, const int* in_sizes, int n_in,
                              void* d_out, int out_size, void* d_ws, size_t ws_size,
                              hipStream_t stream) {
    const float* x = (const float*)d_in[0];   // (4096, 4096) f32
    const float* W = (const float*)d_in[1];   // (4096, 4096) f32
    const float* b = (const float*)d_in[2];   // (4096,) f32
    float* out = (float*)d_out;               // (4096, 4096) f32

    char* xq  = (char*)d_ws;                              // 16 MB: x as i8 (M x K), scale 32
    char* WqT = (char*)d_ws + (size_t)M_DIM * K_DIM;      // 16 MB: sign(W) i8, N x K

    cvt_x_kernel<<<2048, 256, 0, stream>>>(x, xq, M_DIM * K_DIM / 16);
    sign_wt_kernel<<<dim3(N_DIM / 64, K_DIM / 64), dim3(64, 4), 0, stream>>>(W, WqT);
    gemm_bin_kernel<<<dim3(256), dim3(256), 0, stream>>>(xq, WqT, b, out);
}

// Round 9
// 119.498 us; speedup vs baseline: 1.1691x; 1.1691x over previous
//
#include <hip/hip_runtime.h>
#include <hip/hip_bf16.h>
#include <cstdint>
#include <cstddef>

#define M_DIM 4096
#define N_DIM 4096
#define K_DIM 4096
#define KBLKS (K_DIM / 64)    // 64 granule-columns of K=64

using i32x4   = __attribute__((ext_vector_type(4))) int;
using s8x16   = __attribute__((ext_vector_type(16))) char;
using float4v = __attribute__((ext_vector_type(4))) float;

__device__ __forceinline__ i32x4 mfma_i8(i32x4 a, i32x4 b, i32x4 c) {
    return __builtin_amdgcn_mfma_i32_16x16x64_i8(a, b, c, 0, 0, 0);
}

// Granule layout (R5-validated): granule g = (rowblk, kblk), 1024B.
// Slot l*16 <-> (row = rowblk*16 + (l&15), k bytes kblk*64 + (l>>4)*16 .. +16).
// xq:  [M/16][K/64][1024]   WqT: [N/16][K/64][1024]

// ------- pass 1a: x (f32) -> i8 q=clamp(rint(32x),±127), granule-major -------
__global__ __launch_bounds__(256) void cvt_x_kernel(const float* __restrict__ x,
                                                    char* __restrict__ xq) {
    int t = threadIdx.x;
    int g = blockIdx.x * 4 + (t >> 6);     // granule id (16384 total)
    int l = t & 63;
    int rowblk = g >> 6;                   // / KBLKS
    int kblk   = g & 63;
    int row = rowblk * 16 + (l & 15);
    int k0  = kblk * 64 + (l >> 4) * 16;
    const float4v* p = (const float4v*)(x + (size_t)row * K_DIM + k0);
    s8x16 o;
#pragma unroll
    for (int v = 0; v < 4; ++v) {
        float4v f = p[v];
#pragma unroll
        for (int j = 0; j < 4; ++j) {
            float q = __builtin_rintf(f[j] * 32.0f);
            q = fminf(127.0f, fmaxf(-127.0f, q));
            o[v * 4 + j] = (char)(int)q;
        }
    }
    *(s8x16*)(xq + (size_t)g * 1024 + l * 16) = o;
}

// --- pass 1b: W (K x N f32) -> sign -> i8, transposed + granule-major WqT ---
__global__ __launch_bounds__(256) void sign_wt_kernel(const float* __restrict__ W,
                                                      char* __restrict__ WqT) {
    __shared__ char tile_t[64][80];   // [n][k], stride 80 (16B-aligned rows)
    int j0 = blockIdx.x * 64;         // N base
    int k0 = blockIdx.y * 64;         // K base
    int tx = threadIdx.x;             // 0..63 (n on read, n on transpose-store)
    int ty = threadIdx.y;             // 0..3
#pragma unroll
    for (int i = 0; i < 16; ++i) {
        int kk = ty + i * 4;
        float w = W[(size_t)(k0 + kk) * N_DIM + (j0 + tx)];
        tile_t[tx][kk] = (char)((w > 0.f) - (w < 0.f));
    }
    __syncthreads();
    // write 4 granules (rowblks j0/16 .. +4, kblk = k0/64), coalesced b128
    int t = ty * 64 + tx;
    int l = t & 63;
    int nl = (t >> 6) * 16 + (l & 15);
    int k16 = l >> 4;
    i32x4 v = *(const i32x4*)(&tile_t[nl][k16 * 16]);
    size_t g = (size_t)((j0 >> 4) + (t >> 6)) * KBLKS + (k0 >> 6);
    *(i32x4*)(WqT + g * 1024 + l * 16) = v;
}

// --------------- pass 2: zero-LDS i8 MFMA GEMM, operands direct ---------------
// 8 waves (2x4) per 256x256 tile, per-wave 128x64, 16x16x64 i8 MFMA.
// No LDS, no barriers: each wave streams its 12 fragment granules per K-half
// (K=64) straight from L1/L2 as coalesced global_load_dwordx4, dual-banked so
// next-half loads issue under current-half MFMAs. Compiler-counted vmcnt.

#define LOADH(aBank, bBank, kblk) do {                                           \
    _Pragma("unroll")                                                            \
    for (int h = 0; h < 4; ++h)                                                  \
        bBank[h] = *(const i32x4*)(Bb + ((size_t)h * KBLKS + (kblk)) * 1024);    \
    _Pragma("unroll")                                                            \
    for (int f = 0; f < 8; ++f)                                                  \
        aBank[f] = *(const i32x4*)(Ab + ((size_t)f * KBLKS + (kblk)) * 1024);    \
} while (0)

#define MFMAH(aBank, bBank) do {                                                 \
    _Pragma("unroll")                                                            \
    for (int f = 0; f < 8; ++f)                                                  \
        _Pragma("unroll")                                                        \
        for (int h = 0; h < 4; ++h)                                              \
            acc[f][h] = mfma_i8(aBank[f], bBank[h], acc[f][h]);                  \
} while (0)

__global__ __launch_bounds__(512, 1) void gemm_bin_kernel(const char* __restrict__ A,  // xq granule-major
                                                          const char* __restrict__ B,  // WqT granule-major
                                                          const float* __restrict__ bias,
                                                          float* __restrict__ C) {
    // T1: XCD-aware bijective swizzle (256 wgs, 256 % 8 == 0)
    int bid  = blockIdx.x;
    int swz  = (bid & 7) * 32 + (bid >> 3);
    int brow = (swz >> 4) << 8;
    int bcol = (swz & 15) << 8;

    int t    = threadIdx.x;
    int l    = t & 63;
    int wid  = t >> 6;
    int wr   = wid >> 2;   // 0..1  (M half: rows wr*128..+128)
    int wc   = wid & 3;    // 0..3  (N quarter: cols wc*64..+64)

    // fragment granule bases: A rowblks arow0..+8, B rowblks brow0..+4
    size_t arow0 = (size_t)(brow >> 4) + wr * 8;
    size_t brow0 = (size_t)(bcol >> 4) + wc * 4;
    const char* Ab = A + arow0 * KBLKS * 1024 + l * 16;
    const char* Bb = B + brow0 * KBLKS * 1024 + l * 16;

    i32x4 acc[8][4];
#pragma unroll
    for (int i = 0; i < 8; ++i)
#pragma unroll
        for (int j = 0; j < 4; ++j)
            acc[i][j] = (i32x4){0, 0, 0, 0};

    i32x4 aC[8], bC[4], aN[8], bN[4];

    LOADH(aC, bC, 0);
    for (int kb = 0; kb < KBLKS; kb += 2) {
        LOADH(aN, bN, kb + 1);      // next half under current MFMAs
        MFMAH(aC, bC);
        LOADH(aC, bC, kb + 2);      // kb=62 -> kblk 64 over-read: lands in the
                                    // adjacent ws region (valid mem), never used
        MFMAH(aN, bN);
    }

    // epilogue: C/D layout col=lane&15, row=(lane>>4)*4+reg; dequant 1/32
    int klo  = l >> 4;
    int lrow = l & 15;
    int crow = brow + wr * 128 + klo * 4;
    int ccol = bcol + wc * 64 + lrow;
#pragma unroll
    for (int h = 0; h < 4; ++h) {
        int col = ccol + h * 16;
        float bv = bias[col];
#pragma unroll
        for (int f = 0; f < 8; ++f) {
            int row = crow + f * 16;
#pragma unroll
            for (int r = 0; r < 4; ++r)
                C[(size_t)(row + r) * N_DIM + col] =
                    (float)acc[f][h][r] * 0.03125f + bv;
        }
    }
}

extern "C" void kernel_launch(void* const* d_in, const int* in_sizes, int n_in,
                              void* d_out, int out_size, void* d_ws, size_t ws_size,
                              hipStream_t stream) {
    const float* x = (const float*)d_in[0];   // (4096, 4096) f32
    const float* W = (const float*)d_in[1];   // (4096, 4096) f32
    const float* b = (const float*)d_in[2];   // (4096,) f32
    float* out = (float*)d_out;               // (4096, 4096) f32

    char* xq  = (char*)d_ws;                              // 16 MB: x i8, granule-major
    char* WqT = (char*)d_ws + (size_t)M_DIM * K_DIM;      // 16 MB: sign(W) i8, granule-major

    cvt_x_kernel<<<dim3((M_DIM / 16) * (K_DIM / 64) / 4), dim3(256), 0, stream>>>(x, xq);
    sign_wt_kernel<<<dim3(N_DIM / 64, K_DIM / 64), dim3(64, 4), 0, stream>>>(W, WqT);
    gemm_bin_kernel<<<dim3(256), dim3(512), 0, stream>>>(xq, WqT, b, out);
}

// Round 10
// 98.168 us; speedup vs baseline: 1.4231x; 1.2173x over previous
//
#include <hip/hip_runtime.h>
#include <hip/hip_bf16.h>
#include <cstdint>
#include <cstddef>

#define M_DIM 4096
#define N_DIM 4096
#define K_DIM 4096
#define KBLKS (K_DIM / 64)    // 64 granule-columns of K=64
#define NT    (K_DIM / 128)   // 32 K-tiles of BK=128

using i32x4   = __attribute__((ext_vector_type(4))) int;
using s8x16   = __attribute__((ext_vector_type(16))) char;
using float4v = __attribute__((ext_vector_type(4))) float;

__device__ __forceinline__ void gload_lds16(const void* g, void* l) {
    __builtin_amdgcn_global_load_lds(
        (const __attribute__((address_space(1))) uint32_t*)g,
        (__attribute__((address_space(3))) uint32_t*)l, 16, 0, 0);
}

__device__ __forceinline__ i32x4 mfma_i8(i32x4 a, i32x4 b, i32x4 c) {
    return __builtin_amdgcn_mfma_i32_16x16x64_i8(a, b, c, 0, 0, 0);
}

// Granule layout (R5/R9-validated): granule g = (rowblk, kblk), 1024B.
// Slot l*16 <-> (row = rowblk*16 + (l&15), k bytes kblk*64 + (l>>4)*16 .. +16).
// xq:  [M/16][K/64][1024]   WqT: [N/16][K/64][1024]

// ------- pass 1a: x (f32) -> i8 q=clamp(rint(32x),±127), granule-major -------
__global__ __launch_bounds__(256) void cvt_x_kernel(const float* __restrict__ x,
                                                    char* __restrict__ xq) {
    int t = threadIdx.x;
    int g = blockIdx.x * 4 + (t >> 6);     // granule id (16384 total)
    int l = t & 63;
    int rowblk = g >> 6;                   // / KBLKS
    int kblk   = g & 63;
    int row = rowblk * 16 + (l & 15);
    int k0  = kblk * 64 + (l >> 4) * 16;
    const float4v* p = (const float4v*)(x + (size_t)row * K_DIM + k0);
    s8x16 o;
#pragma unroll
    for (int v = 0; v < 4; ++v) {
        float4v f = p[v];
#pragma unroll
        for (int j = 0; j < 4; ++j) {
            float q = __builtin_rintf(f[j] * 32.0f);
            q = fminf(127.0f, fmaxf(-127.0f, q));
            o[v * 4 + j] = (char)(int)q;
        }
    }
    *(s8x16*)(xq + (size_t)g * 1024 + l * 16) = o;
}

// --- pass 1b: W (K x N f32) -> sign -> i8, transposed + granule-major WqT ---
__global__ __launch_bounds__(256) void sign_wt_kernel(const float* __restrict__ W,
                                                      char* __restrict__ WqT) {
    __shared__ char tile_t[64][80];   // [n][k], stride 80 (16B-aligned rows)
    int j0 = blockIdx.x * 64;         // N base
    int k0 = blockIdx.y * 64;         // K base
    int tx = threadIdx.x;             // 0..63
    int ty = threadIdx.y;             // 0..3
#pragma unroll
    for (int i = 0; i < 16; ++i) {
        int kk = ty + i * 4;
        float w = W[(size_t)(k0 + kk) * N_DIM + (j0 + tx)];
        tile_t[tx][kk] = (char)((w > 0.f) - (w < 0.f));
    }
    __syncthreads();
    int t = ty * 64 + tx;
    int l = t & 63;
    int nl = (t >> 6) * 16 + (l & 15);
    int k16 = l >> 4;
    i32x4 v = *(const i32x4*)(&tile_t[nl][k16 * 16]);
    size_t g = (size_t)((j0 >> 4) + (t >> 6)) * KBLKS + (k0 >> 6);
    *(i32x4*)(WqT + g * 1024 + l * 16) = v;
}

// ------------- pass 2: 256x256-tile i8 GEMM, split-pipe operands -------------
// A: LDS double-buffered (128KB/tile reads, shared by 4 waves per row-half).
// B: direct global->register granule loads (R9-verified), dual-banked so
//    tile kt+1's B loads issue under tile kt's MFMAs (VMEM pipe, else idle).
// One __syncthreads() per tile = vmcnt(0)+lgkm(0)+barrier: drains the A-stage
// gloads AND the B-register loads (both issued a full compute phase earlier),
// and guards the A-dbuf write-after-read. 8 waves (2x4), per-wave 128x64.

#define SCHED0 __builtin_amdgcn_sched_barrier(0)

// A stage: 32 granules (16 rowblks x 2 kk), 4 gload16/thread.
// instr i covers granule g = i*8 + wid  (rb = i*4 + (wid>>1), kk = wid&1)
#define STAGE_A(p, kt) do {                                                      \
    _Pragma("unroll")                                                            \
    for (int i = 0; i < 4; ++i)                                                  \
        gload_lds16(AsrcW + (size_t)i * 4 * KBLKS * 1024 + (size_t)(kt) * 2048, \
                    AdstW + (p) * 32768 + i * 8192);                             \
} while (0)

// B direct load: bank[nq][kk] <- granule (brow0B + nq, kt*2 + kk)
#define LOADB(bank, kt) do {                                                     \
    _Pragma("unroll")                                                            \
    for (int nq = 0; nq < 4; ++nq)                                               \
        _Pragma("unroll")                                                        \
        for (int kk = 0; kk < 2; ++kk)                                           \
            bank[nq][kk] = *(const i32x4*)(BsrcW +                               \
                ((size_t)nq * KBLKS + (size_t)(kt) * 2 + kk) * 1024);            \
} while (0)

#define RD_A(p, mq, kk)                                                          \
    (*(const i32x4*)(ldsc + (p) * 32768 + ((wr * 8 + (mq)) * 2 + (kk)) * 1024 + \
                     (l << 4)))

#define HALF(p, kk, BC) do {                                                     \
    _Pragma("unroll")                                                            \
    for (int mq = 0; mq < 8; ++mq) aF[mq] = RD_A(p, mq, kk);                     \
    __builtin_amdgcn_s_setprio(1);                                               \
    _Pragma("unroll")                                                            \
    for (int mq = 0; mq < 8; ++mq)                                               \
        _Pragma("unroll")                                                        \
        for (int nq = 0; nq < 4; ++nq)                                           \
            acc[mq][nq] = mfma_i8(aF[mq], BC[nq][kk], acc[mq][nq]);              \
    __builtin_amdgcn_s_setprio(0);                                               \
} while (0)

#define TILE(kt, p, BC, BN) do {                                                 \
    if ((kt) + 1 < NT) { STAGE_A((p) ^ 1, (kt) + 1); LOADB(BN, (kt) + 1); }      \
    SCHED0;                                                                      \
    HALF(p, 0, BC);                                                              \
    HALF(p, 1, BC);                                                              \
    __syncthreads();                                                             \
    SCHED0;                                                                      \
} while (0)

__global__ __launch_bounds__(512, 2) void gemm_bin_kernel(const char* __restrict__ A,  // xq granule-major
                                                          const char* __restrict__ B,  // WqT granule-major
                                                          const float* __restrict__ bias,
                                                          float* __restrict__ C) {
    // 64 KiB: A only, [2 buf][32 granules x 1024B]
    __shared__ __align__(16) unsigned char lds[65536];

    // T1: XCD-aware bijective swizzle (256 wgs, 256 % 8 == 0)
    int bid  = blockIdx.x;
    int swz  = (bid & 7) * 32 + (bid >> 3);
    int brow = (swz >> 4) << 8;
    int bcol = (swz & 15) << 8;

    int t    = threadIdx.x;
    int l    = t & 63;
    int wid  = t >> 6;
    int wr   = wid >> 2;   // 0..1  (M half: rows wr*128..+128)
    int wc   = wid & 3;    // 0..3  (N quarter: cols wc*64..+64)

    // A staging source (granule-major): base for instr series
    size_t arow0 = (size_t)(brow >> 4);
    const char* AsrcW = A + ((arow0 + (wid >> 1)) * KBLKS + (wid & 1)) * 1024
                          + (l << 4);
    unsigned char* AdstW = lds + wid * 1024 + (l << 4);

    // B direct source: wave's 4 rowblks
    size_t brow0B = (size_t)(bcol >> 4) + wc * 4;
    const char* BsrcW = B + brow0B * KBLKS * 1024 + (l << 4);

    const char* ldsc = (const char*)lds;

    i32x4 acc[8][4];
#pragma unroll
    for (int i = 0; i < 8; ++i)
#pragma unroll
        for (int j = 0; j < 4; ++j)
            acc[i][j] = (i32x4){0, 0, 0, 0};

    i32x4 aF[8], bC[4][2], bN[4][2];

    // prologue: stage tile 0 (A->LDS, B->regs); full drain
    STAGE_A(0, 0);
    LOADB(bC, 0);
    __syncthreads();
    SCHED0;

    for (int kt2 = 0; kt2 < NT; kt2 += 2) {
        TILE(kt2, 0, bC, bN);
        TILE(kt2 + 1, 1, bN, bC);
    }

    // epilogue: C/D layout col=lane&15, row=(lane>>4)*4+reg; dequant 1/32
    int klo  = l >> 4;
    int lrow = l & 15;
    int crow = brow + wr * 128 + klo * 4;
    int ccol = bcol + wc * 64 + lrow;
#pragma unroll
    for (int nq = 0; nq < 4; ++nq) {
        int col = ccol + nq * 16;
        float bv = bias[col];
#pragma unroll
        for (int mq = 0; mq < 8; ++mq) {
            int row = crow + mq * 16;
#pragma unroll
            for (int r = 0; r < 4; ++r)
                C[(size_t)(row + r) * N_DIM + col] =
                    (float)acc[mq][nq][r] * 0.03125f + bv;
        }
    }
}

extern "C" void kernel_launch(void* const* d_in, const int* in_sizes, int n_in,
                              void* d_out, int out_size, void* d_ws, size_t ws_size,
                              hipStream_t stream) {
    const float* x = (const float*)d_in[0];   // (4096, 4096) f32
    const float* W = (const float*)d_in[1];   // (4096, 4096) f32
    const float* b = (const float*)d_in[2];   // (4096,) f32
    float* out = (float*)d_out;               // (4096, 4096) f32

    char* xq  = (char*)d_ws;                              // 16 MB: x i8, granule-major
    char* WqT = (char*)d_ws + (size_t)M_DIM * K_DIM;      // 16 MB: sign(W) i8, granule-major

    cvt_x_kernel<<<dim3((M_DIM / 16) * (K_DIM / 64) / 4), dim3(256), 0, stream>>>(x, xq);
    sign_wt_kernel<<<dim3(N_DIM / 64, K_DIM / 64), dim3(64, 4), 0, stream>>>(W, WqT);
    gemm_bin_kernel<<<dim3(256), dim3(512), 0, stream>>>(xq, WqT, b, out);
}